// Round 2
// baseline (229528.735 us; speedup 1.0000x reference)
//
#include <hip/hip_runtime.h>

#define NB   64      // batch
#define TT   512     // timesteps
#define HH   512     // hidden

__device__ __forceinline__ float sigm(float x) {
    return 1.f / (1.f + expf(-x));
}

// init hidden state: hs[l][k][b] = hidden0[l][0][k]
__global__ void k_init(const float* __restrict__ h0, float* __restrict__ hs) {
    int idx = blockIdx.x * blockDim.x + threadIdx.x;   // 65536 total
    int l = idx >> 15;
    int rem = idx & 32767;
    int k = rem >> 6;
    hs[idx] = h0[(l << 9) + k];
}

// transpose x patch for step t: xinT[k][b] = x[b, t*512+k]
__global__ void k_xt(const float* __restrict__ x, float* __restrict__ xinT, int t) {
    int b = blockIdx.x;        // 64
    int k = threadIdx.x;       // 512
    xinT[k * 64 + b] = x[(size_t)b * 262144 + (size_t)t * 512 + k];
}

// GRU cell: one wave per output j (512 waves), lane = batch row
__global__ void k_gru(const float* __restrict__ xinT, const float* __restrict__ hT,
                      const float* __restrict__ Wih, const float* __restrict__ Whh,
                      const float* __restrict__ bih, const float* __restrict__ bhh,
                      float* __restrict__ hpT) {
    int lane = threadIdx.x & 63;
    int j = __builtin_amdgcn_readfirstlane((blockIdx.x * blockDim.x + threadIdx.x) >> 6);
    const float* wi_r = Wih + (size_t)j * 512;
    const float* wi_z = Wih + (size_t)(512 + j) * 512;
    const float* wi_n = Wih + (size_t)(1024 + j) * 512;
    const float* wh_r = Whh + (size_t)j * 512;
    const float* wh_z = Whh + (size_t)(512 + j) * 512;
    const float* wh_n = Whh + (size_t)(1024 + j) * 512;
    float ir = 0.f, iz = 0.f, in_ = 0.f, hr = 0.f, hz = 0.f, hn = 0.f;
#pragma unroll 4
    for (int k = 0; k < 512; k++) {
        float xv = xinT[k * 64 + lane];
        float hv = hT[k * 64 + lane];
        ir = fmaf(wi_r[k], xv, ir);
        iz = fmaf(wi_z[k], xv, iz);
        in_ = fmaf(wi_n[k], xv, in_);
        hr = fmaf(wh_r[k], hv, hr);
        hz = fmaf(wh_z[k], hv, hz);
        hn = fmaf(wh_n[k], hv, hn);
    }
    ir += bih[j];        hr += bhh[j];
    iz += bih[512 + j];  hz += bhh[512 + j];
    in_ += bih[1024 + j]; hn += bhh[1024 + j];
    float r = sigm(ir + hr);
    float z = sigm(iz + hz);
    float n = tanhf(in_ + r * hn);
    float h = hT[j * 64 + lane];
    hpT[j * 64 + lane] = (1.f - z) * n + z * h;
}

// bitonic sort of 512 features per row (ascending); one block per row
__global__ void k_sort(const float* __restrict__ hpT, float* __restrict__ sT) {
    __shared__ float v[512];
    int b = blockIdx.x;        // 64
    int t = threadIdx.x;       // 256
    v[t] = hpT[t * 64 + b];
    v[t + 256] = hpT[(t + 256) * 64 + b];
    __syncthreads();
    for (unsigned k2 = 2; k2 <= 512; k2 <<= 1) {
        for (unsigned jj = k2 >> 1; jj > 0; jj >>= 1) {
            for (int s = 0; s < 2; s++) {
                int i = t + s * 256;
                int l = i ^ (int)jj;
                if (l > i) {
                    bool up = ((i & k2) == 0);
                    float a = v[i], c = v[l];
                    if ((a > c) == up) { v[i] = c; v[l] = a; }
                }
            }
            __syncthreads();
        }
    }
    sT[t * 64 + b] = v[t];
    sT[(t + 256) * 64 + b] = v[t + 256];
}

// a1: y1[c] for c = i*512 + j; src row i=0 -> h, i=1 -> sorted
__global__ void k_a1(const float* __restrict__ hpT, const float* __restrict__ sT,
                     const float* __restrict__ A, float* __restrict__ y1T) {
    int lane = threadIdx.x & 63;
    int c = __builtin_amdgcn_readfirstlane((blockIdx.x * blockDim.x + threadIdx.x) >> 6);
    int i = c >> 9;
    int j = c & 511;
    const float* src = i ? sT : hpT;
    const float* w = A + (size_t)j * 512;
    float acc = 0.f;
#pragma unroll 4
    for (int k = 0; k < 512; k++)
        acc = fmaf(w[k], src[k * 64 + lane], acc);
    y1T[c * 64 + lane] = acc;
}

// a2/a3 with shuffle folded in: out[g*256+jj] = sum_m A[jj,m] * in[(m%4)*256 + g*64 + m/4]
__global__ void k_a23(const float* __restrict__ inT, const float* __restrict__ A,
                      float* __restrict__ outT, int do_relu) {
    int lane = threadIdx.x & 63;
    int c = __builtin_amdgcn_readfirstlane((blockIdx.x * blockDim.x + threadIdx.x) >> 6);
    int g = c >> 8;
    int jj = c & 255;
    const float* w = A + (size_t)jj * 256;
    float acc = 0.f;
#pragma unroll 4
    for (int m = 0; m < 256; m++) {
        int idx = ((m & 3) << 8) + (g << 6) + (m >> 2);
        acc = fmaf(w[m], inT[idx * 64 + lane], acc);
    }
    if (do_relu) acc = fmaxf(acc, 0.f);
    outT[c * 64 + lane] = acc;
}

// a4 + sigmoid + h*scores; updates recurrent state, optionally writes final output
__global__ void k_a4(const float* __restrict__ y3T, const float* __restrict__ A,
                     const float* __restrict__ hpT, float* __restrict__ hsl,
                     float* __restrict__ outp, int t) {
    int lane = threadIdx.x & 63;
    int j = __builtin_amdgcn_readfirstlane((blockIdx.x * blockDim.x + threadIdx.x) >> 6);
    const float* w = A + (size_t)j * 1024;
    float acc = 0.f;
#pragma unroll 4
    for (int k = 0; k < 1024; k++)
        acc = fmaf(w[k], y3T[k * 64 + lane], acc);
    float sc = sigm(acc);
    float hnew = hpT[j * 64 + lane] * sc;
    hsl[j * 64 + lane] = hnew;
    if (outp)
        outp[(size_t)lane * 262144 + (size_t)t * 512 + j] = hnew;
}

extern "C" void kernel_launch(void* const* d_in, const int* in_sizes, int n_in,
                              void* d_out, int out_size, void* d_ws, size_t ws_size,
                              hipStream_t stream) {
    const float* x   = (const float*)d_in[0];
    const float* h0  = (const float*)d_in[1];
    const float* wih = (const float*)d_in[2];
    const float* whh = (const float*)d_in[3];
    const float* bih = (const float*)d_in[4];
    const float* bhh = (const float*)d_in[5];
    const float* a1  = (const float*)d_in[6];
    const float* a2  = (const float*)d_in[7];
    const float* a3  = (const float*)d_in[8];
    const float* a4  = (const float*)d_in[9];
    float* ws = (float*)d_ws;

    float* hs   = ws;            // 2 * 32768  (layer states, [l][k][b])
    float* hpT  = ws + 65536;    // 32768
    float* sT   = ws + 98304;    // 32768
    float* y1T  = ws + 131072;   // 65536
    float* y2T  = ws + 196608;   // 65536
    float* y3T  = ws + 262144;   // 65536
    float* xinT = ws + 327680;   // 32768
    float* out = (float*)d_out;

    hipLaunchKernelGGL(k_init, dim3(256), dim3(256), 0, stream, h0, hs);

    for (int t = 0; t < TT; t++) {
        hipLaunchKernelGGL(k_xt, dim3(64), dim3(512), 0, stream, x, xinT, t);
        for (int l = 0; l < 2; l++) {
            const float* xin = (l == 0) ? xinT : hs;   // layer1 input = layer0 new state
            float* hsl = hs + l * 32768;
            hipLaunchKernelGGL(k_gru, dim3(128), dim3(256), 0, stream,
                               xin, hsl,
                               wih + (size_t)l * 786432, whh + (size_t)l * 786432,
                               bih + (size_t)l * 1536,  bhh + (size_t)l * 1536, hpT);
            hipLaunchKernelGGL(k_sort, dim3(64), dim3(256), 0, stream, hpT, sT);
            hipLaunchKernelGGL(k_a1, dim3(256), dim3(256), 0, stream,
                               hpT, sT, a1 + (size_t)l * 262144, y1T);
            hipLaunchKernelGGL(k_a23, dim3(256), dim3(256), 0, stream,
                               y1T, a2 + (size_t)l * 65536, y2T, 0);
            hipLaunchKernelGGL(k_a23, dim3(256), dim3(256), 0, stream,
                               y2T, a3 + (size_t)l * 65536, y3T, 1);
            hipLaunchKernelGGL(k_a4, dim3(128), dim3(256), 0, stream,
                               y3T, a4 + (size_t)l * 524288, hpT, hsl,
                               (l == 1) ? out : (float*)nullptr, t);
        }
    }
}

// Round 3
// 216564.941 us; speedup vs baseline: 1.0599x; 1.0599x over previous
//
#include <hip/hip_runtime.h>

#define NBLK 256
#define SCOPE_AGENT __HIP_MEMORY_SCOPE_AGENT

__device__ __forceinline__ float sigm(float x) { return 1.f / (1.f + expf(-x)); }

// ---- two-level global barrier: 16 L1 counters (16 blocks each) -> 1 L2 counter -> gen bump
__device__ __forceinline__ void gbar(unsigned* c1, unsigned* c2, unsigned* gen) {
    __syncthreads();
    if (threadIdx.x == 0) {
        unsigned g = __hip_atomic_load(gen, __ATOMIC_RELAXED, SCOPE_AGENT);
        unsigned a = __hip_atomic_fetch_add(&c1[blockIdx.x & 15], 1u, __ATOMIC_ACQ_REL, SCOPE_AGENT);
        bool last = false;
        if (a == 15u) {
            unsigned b = __hip_atomic_fetch_add(c2, 1u, __ATOMIC_ACQ_REL, SCOPE_AGENT);
            if (b == 15u) {
                last = true;
                for (int i = 0; i < 16; i++)
                    __hip_atomic_store(&c1[i], 0u, __ATOMIC_RELAXED, SCOPE_AGENT);
                __hip_atomic_store(c2, 0u, __ATOMIC_RELAXED, SCOPE_AGENT);
                __hip_atomic_store(gen, g + 1u, __ATOMIC_RELEASE, SCOPE_AGENT);
            }
        }
        if (!last) {
            while (__hip_atomic_load(gen, __ATOMIC_RELAXED, SCOPE_AGENT) == g)
                __builtin_amdgcn_s_sleep(2);
            (void)__hip_atomic_load(gen, __ATOMIC_ACQUIRE, SCOPE_AGENT);  // acquire released data
        }
    }
    __syncthreads();
}

// init hidden state + zero barrier counters
__global__ void k_init(const float* __restrict__ h0, float* __restrict__ ws) {
    int idx = blockIdx.x * blockDim.x + threadIdx.x;   // 65536
    int l = idx >> 15, k = (idx & 32767) >> 6;
    ws[idx] = h0[(l << 9) + k];
    if (idx < 18) ((unsigned*)(ws + 327680))[idx] = 0u;
}

__global__ void __launch_bounds__(512, 1)
persist(const float* __restrict__ x,
        const float* __restrict__ wih, const float* __restrict__ whh,
        const float* __restrict__ bih, const float* __restrict__ bhh,
        const float* __restrict__ a1, const float* __restrict__ a2,
        const float* __restrict__ a3, const float* __restrict__ a4,
        float* __restrict__ ws, float* __restrict__ out) {
    __shared__ float wA[2][2][3072];   // [l][feat][ r(1024) | z(1024) | in_x(512) | hn_h(512) ]
    __shared__ float wC1[2][4][512];   // a1 rows 4B..4B+3
    __shared__ float wC2[2][4][256];   // a2 rows
    __shared__ float wC3[2][4][256];   // a3 rows
    __shared__ float wD[2][2][1024];   // a4 rows 2B..2B+1
    __shared__ float bb[2][2][4];      // gate biases (r,z combined; in; hn)
    __shared__ float red[8][64];
    __shared__ float sH[2][64];        // h' for this block's 2 features

    const int tid = threadIdx.x, w = tid >> 6, lane = tid & 63, bid = blockIdx.x;

    // ---- preload weight slices into LDS (once) ----
    for (int i = tid; i < 12288; i += 512) {            // wA
        int l = i / 6144, rem = i % 6144, f = rem / 3072, idx = rem % 3072;
        int j = 2 * bid + f;
        const float* wi = wih + l * 786432;
        const float* wh = whh + l * 786432;
        float v;
        if (idx < 512)       v = wi[j * 512 + idx];
        else if (idx < 1024) v = wh[j * 512 + (idx - 512)];
        else if (idx < 1536) v = wi[(512 + j) * 512 + (idx - 1024)];
        else if (idx < 2048) v = wh[(512 + j) * 512 + (idx - 1536)];
        else if (idx < 2560) v = wi[(1024 + j) * 512 + (idx - 2048)];
        else                 v = wh[(1024 + j) * 512 + (idx - 2560)];
        wA[l][f][idx] = v;
    }
    for (int i = tid; i < 4096; i += 512) {             // wC1
        int l = i / 2048, rem = i % 2048, r = rem / 512, k = rem % 512;
        int c = 4 * bid + r;
        wC1[l][r][k] = a1[l * 262144 + (c & 511) * 512 + k];
    }
    for (int i = tid; i < 2048; i += 512) {             // wC2
        int l = i / 1024, rem = i % 1024, r = rem / 256, m = rem % 256;
        int c2 = 4 * bid + r;
        wC2[l][r][m] = a2[l * 65536 + (c2 & 255) * 256 + m];
    }
    for (int i = tid; i < 2048; i += 512) {             // wC3
        int l = i / 1024, rem = i % 1024, r = rem / 256, m = rem % 256;
        int c2 = 4 * bid + r;
        wC3[l][r][m] = a3[l * 65536 + (c2 & 255) * 256 + m];
    }
    for (int i = tid; i < 4096; i += 512) {             // wD
        int l = i / 2048, rem = i % 2048, f = rem / 1024, k = rem % 1024;
        int j = 2 * bid + f;
        wD[l][f][k] = a4[l * 524288 + j * 1024 + k];
    }
    if (tid < 16) {                                     // biases
        int l = tid / 8, f = (tid / 4) & 1, g = tid & 3;
        int j = 2 * bid + f;
        float v;
        if (g == 0)      v = bih[l * 1536 + j] + bhh[l * 1536 + j];
        else if (g == 1) v = bih[l * 1536 + 512 + j] + bhh[l * 1536 + 512 + j];
        else if (g == 2) v = bih[l * 1536 + 1024 + j];
        else             v = bhh[l * 1536 + 1024 + j];
        bb[l][f][g] = v;
    }
    __syncthreads();

    float* hsG = ws;             // [2][512][64]
    float* hPg = ws + 65536;     // [512][64]
    float* sGg = ws + 98304;     // [512][64]
    float* y1G = ws + 131072;    // [1024][64]
    float* y2G = ws + 196608;    // [1024][64]
    float* uG  = ws + 262144;    // [1024][64]
    unsigned* c1p  = (unsigned*)(ws + 327680);
    unsigned* c2p  = c1p + 16;
    unsigned* genp = c1p + 17;

    for (int t = 0; t < 512; t++) {
        for (int l = 0; l < 2; l++) {
            // ---- Stage A: GRU gates + h' ----
            {
                int f = w & 1, gate = w >> 1;
                float acc = 0.f;
                if (gate < 2) {
                    const float* wr = &wA[l][f][gate * 1024];
                    if (l == 0) {
                        const float* xp = x + (size_t)lane * 262144 + (size_t)t * 512;
#pragma unroll 8
                        for (int k = 0; k < 512; k++) acc = fmaf(wr[k], xp[k], acc);
                    } else {
#pragma unroll 8
                        for (int k = 0; k < 512; k++) acc = fmaf(wr[k], hsG[k * 64 + lane], acc);
                    }
                    const float* hb = hsG + l * 32768;
#pragma unroll 8
                    for (int k = 0; k < 512; k++) acc = fmaf(wr[512 + k], hb[k * 64 + lane], acc);
                } else if (gate == 2) {
                    const float* wr = &wA[l][f][2048];
                    if (l == 0) {
                        const float* xp = x + (size_t)lane * 262144 + (size_t)t * 512;
#pragma unroll 8
                        for (int k = 0; k < 512; k++) acc = fmaf(wr[k], xp[k], acc);
                    } else {
#pragma unroll 8
                        for (int k = 0; k < 512; k++) acc = fmaf(wr[k], hsG[k * 64 + lane], acc);
                    }
                } else {
                    const float* wr = &wA[l][f][2560];
                    const float* hb = hsG + l * 32768;
#pragma unroll 8
                    for (int k = 0; k < 512; k++) acc = fmaf(wr[k], hb[k * 64 + lane], acc);
                }
                red[w][lane] = acc;
                __syncthreads();
                if (w == 0) {
                    for (int f2 = 0; f2 < 2; f2++) {
                        int j2 = 2 * bid + f2;
                        float r  = sigm(red[0 + f2][lane] + bb[l][f2][0]);
                        float z  = sigm(red[2 + f2][lane] + bb[l][f2][1]);
                        float hn = red[6 + f2][lane] + bb[l][f2][3];
                        float n  = tanhf(red[4 + f2][lane] + bb[l][f2][2] + r * hn);
                        float hp = (1.f - z) * n + z * hsG[l * 32768 + j2 * 64 + lane];
                        sH[f2][lane] = hp;
                        hPg[j2 * 64 + lane] = hp;
                    }
                }
            }
            gbar(c1p, c2p, genp);

            // ---- Stage B: rank-sort scatter ----
            {
                int f = w & 1, ch = w >> 1, j = 2 * bid + f;
                float v = sH[f][lane];
                int cnt = 0, k0 = ch * 128;
#pragma unroll 8
                for (int k = k0; k < k0 + 128; k++) {
                    float hv = hPg[k * 64 + lane];
                    cnt += (hv < v) || (hv == v && k < j);
                }
                red[w][lane] = (float)cnt;
                __syncthreads();
                if (w == 0) {
                    for (int f2 = 0; f2 < 2; f2++) {
                        int rk = (int)(red[0 + f2][lane] + red[2 + f2][lane] +
                                       red[4 + f2][lane] + red[6 + f2][lane]);
                        sGg[rk * 64 + lane] = sH[f2][lane];
                    }
                }
            }
            gbar(c1p, c2p, genp);

            // ---- Stage C1: a1 ----
            {
                int r = w >> 1, kh = w & 1, c = 4 * bid + r;
                const float* src = (c >= 512) ? sGg : hPg;
                const float* wr = &wC1[l][r][0];
                float acc = 0.f;
                int k0 = kh * 256;
#pragma unroll 8
                for (int k = k0; k < k0 + 256; k++) acc = fmaf(wr[k], src[k * 64 + lane], acc);
                red[w][lane] = acc;
                __syncthreads();
                if (w == 0)
                    for (int r2 = 0; r2 < 4; r2++)
                        y1G[(4 * bid + r2) * 64 + lane] = red[r2 * 2][lane] + red[r2 * 2 + 1][lane];
            }
            gbar(c1p, c2p, genp);

            // ---- Stage C2: shuffle + a2 ----
            {
                int r = w >> 1, kh = w & 1, c2 = 4 * bid + r, g = c2 >> 8;
                const float* wr = &wC2[l][r][0];
                float acc = 0.f;
                int m0 = kh * 128;
#pragma unroll 8
                for (int m = m0; m < m0 + 128; m++) {
                    int idx = ((m & 3) << 8) + (g << 6) + (m >> 2);
                    acc = fmaf(wr[m], y1G[idx * 64 + lane], acc);
                }
                red[w][lane] = acc;
                __syncthreads();
                if (w == 0)
                    for (int r2 = 0; r2 < 4; r2++)
                        y2G[(4 * bid + r2) * 64 + lane] = red[r2 * 2][lane] + red[r2 * 2 + 1][lane];
            }
            gbar(c1p, c2p, genp);

            // ---- Stage C3: shuffle + a3 + ReLU ----
            {
                int r = w >> 1, kh = w & 1, c2 = 4 * bid + r, g = c2 >> 8;
                const float* wr = &wC3[l][r][0];
                float acc = 0.f;
                int m0 = kh * 128;
#pragma unroll 8
                for (int m = m0; m < m0 + 128; m++) {
                    int idx = ((m & 3) << 8) + (g << 6) + (m >> 2);
                    acc = fmaf(wr[m], y2G[idx * 64 + lane], acc);
                }
                red[w][lane] = acc;
                __syncthreads();
                if (w == 0)
                    for (int r2 = 0; r2 < 4; r2++)
                        uG[(4 * bid + r2) * 64 + lane] =
                            fmaxf(red[r2 * 2][lane] + red[r2 * 2 + 1][lane], 0.f);
            }
            gbar(c1p, c2p, genp);

            // ---- Stage D: a4 + sigmoid + h'*scores ----
            {
                int f = w & 1, ch = w >> 1;
                const float* wr = &wD[l][f][0];
                float acc = 0.f;
                int k0 = ch * 256;
#pragma unroll 8
                for (int k = k0; k < k0 + 256; k++) acc = fmaf(wr[k], uG[k * 64 + lane], acc);
                red[w][lane] = acc;
                __syncthreads();
                if (w == 0) {
                    for (int f2 = 0; f2 < 2; f2++) {
                        float s4 = red[0 + f2][lane] + red[2 + f2][lane] +
                                   red[4 + f2][lane] + red[6 + f2][lane];
                        float hnew = sH[f2][lane] * sigm(s4);
                        hsG[l * 32768 + (2 * bid + f2) * 64 + lane] = hnew;
                        if (l == 1)
                            out[(size_t)lane * 262144 + (size_t)t * 512 + 2 * bid + f2] = hnew;
                    }
                }
            }
            gbar(c1p, c2p, genp);
        }
    }
}

extern "C" void kernel_launch(void* const* d_in, const int* in_sizes, int n_in,
                              void* d_out, int out_size, void* d_ws, size_t ws_size,
                              hipStream_t stream) {
    const float* x   = (const float*)d_in[0];
    const float* h0  = (const float*)d_in[1];
    const float* wih = (const float*)d_in[2];
    const float* whh = (const float*)d_in[3];
    const float* bih = (const float*)d_in[4];
    const float* bhh = (const float*)d_in[5];
    const float* a1  = (const float*)d_in[6];
    const float* a2  = (const float*)d_in[7];
    const float* a3  = (const float*)d_in[8];
    const float* a4  = (const float*)d_in[9];
    float* ws  = (float*)d_ws;
    float* out = (float*)d_out;

    hipLaunchKernelGGL(k_init, dim3(256), dim3(256), 0, stream, h0, ws);

    void* args[] = {&x, &wih, &whh, &bih, &bhh, &a1, &a2, &a3, &a4, &ws, &out};
    hipLaunchCooperativeKernel((void*)persist, dim3(NBLK), dim3(512), args, 0, stream);
}

// Round 4
// 118120.007 us; speedup vs baseline: 1.9432x; 1.8334x over previous
//
#include <hip/hip_runtime.h>

#define SCOPE_AGENT __HIP_MEMORY_SCOPE_AGENT

// ws layout (float offsets)
#define OFF_HS    0          // [2][512][64] hidden states
#define OFF_HP    65536      // [512][64] h'
#define OFF_SG    98304      // [512][64] sorted
#define OFF_U     131072     // [1024][64] u = relu(M [h;s])
#define OFF_CTR   196608     // 18 uints barrier
#define OFF_T1    262144     // [2][1024][1024] compose scratch
#define OFF_M     2359296    // [2][1024][1024] composed M
#define OFF_XT    4456448    // [512][512][64] transposed x
#define WS_FULL   21233664   // floats incl xT
#define WS_MIN    4456448    // floats w/o xT

__device__ __forceinline__ float sigm(float x) { return 1.f / (1.f + expf(-x)); }

__device__ __forceinline__ void gbar(unsigned* c1, unsigned* c2, unsigned* gen) {
    __syncthreads();
    if (threadIdx.x == 0) {
        unsigned g = __hip_atomic_load(gen, __ATOMIC_RELAXED, SCOPE_AGENT);
        unsigned a = __hip_atomic_fetch_add(&c1[blockIdx.x & 15], 1u, __ATOMIC_ACQ_REL, SCOPE_AGENT);
        bool last = false;
        if (a == 15u) {
            unsigned b = __hip_atomic_fetch_add(c2, 1u, __ATOMIC_ACQ_REL, SCOPE_AGENT);
            if (b == 15u) {
                last = true;
                for (int i = 0; i < 16; i++)
                    __hip_atomic_store(&c1[i], 0u, __ATOMIC_RELAXED, SCOPE_AGENT);
                __hip_atomic_store(c2, 0u, __ATOMIC_RELAXED, SCOPE_AGENT);
                __hip_atomic_store(gen, g + 1u, __ATOMIC_RELEASE, SCOPE_AGENT);
            }
        }
        if (!last) {
            while (__hip_atomic_load(gen, __ATOMIC_RELAXED, SCOPE_AGENT) == g)
                __builtin_amdgcn_s_sleep(1);
            (void)__hip_atomic_load(gen, __ATOMIC_ACQUIRE, SCOPE_AGENT);
        }
    }
    __syncthreads();
}

__global__ void k_init(const float* __restrict__ h0, float* __restrict__ ws) {
    int idx = blockIdx.x * blockDim.x + threadIdx.x;   // 65536
    int l = idx >> 15, k = (idx & 32767) >> 6;
    ws[OFF_HS + idx] = h0[(l << 9) + k];
    if (idx < 18) ((unsigned*)(ws + OFF_CTR))[idx] = 0u;
}

// transpose x -> xT[t][k][b]
__global__ void k_xtk(const float* __restrict__ x, float* __restrict__ xT) {
    __shared__ float tile[64][65];
    int t = blockIdx.x >> 3, kc = blockIdx.x & 7;
    int k = threadIdx.x & 63, b0 = threadIdx.x >> 6;
    for (int i = 0; i < 16; i++) {
        int b = i * 4 + b0;
        tile[k][b] = x[(size_t)b * 262144 + (size_t)t * 512 + kc * 64 + k];
    }
    __syncthreads();
    int b2 = threadIdx.x & 63, k0 = threadIdx.x >> 6;
    for (int i = 0; i < 16; i++) {
        int k2 = i * 4 + k0;
        xT[((size_t)t * 512 + kc * 64 + k2) * 64 + b2] = tile[k2][b2];
    }
}

// T1 = C2p * C1 : T1[l][c][col] = sum over m with (m&3)>>1==col>>9 of A2[jj,m]*A1[j(m)][col&511]
__global__ void k_t1(const float* __restrict__ a1, const float* __restrict__ a2,
                     float* __restrict__ T1) {
    int l = blockIdx.x >> 10, c = blockIdx.x & 1023;
    int g = c >> 8, jj = c & 255;
    __shared__ float sA2[256];
    sA2[threadIdx.x] = a2[l * 65536 + jj * 256 + threadIdx.x];
    __syncthreads();
    const float* A1l = a1 + l * 262144;
    for (int colq = 0; colq < 4; colq++) {
        int col = colq * 256 + threadIdx.x;
        int half = col >> 9, cm = col & 511;
        float acc = 0.f;
#pragma unroll 4
        for (int q = 0; q < 64; q++) {
            int a0 = 2 * half;
            int j0 = g * 64 + q;
            acc = fmaf(sA2[4 * q + a0],     A1l[j0 * 512 + cm], acc);
            acc = fmaf(sA2[4 * q + a0 + 1], A1l[(j0 + 256) * 512 + cm], acc);
        }
        T1[((size_t)(l << 10) + c) * 1024 + col] = acc;
    }
}

// M = C3p * T1 : M[l][c][col] = sum_m A3[jj,m] * T1[l][p1(m,g)][col]
__global__ void k_m(const float* __restrict__ a3, const float* __restrict__ T1,
                    float* __restrict__ M) {
    int l = blockIdx.x >> 10, c = blockIdx.x & 1023;
    int g = c >> 8, jj = c & 255;
    __shared__ float sA3[256];
    sA3[threadIdx.x] = a3[l * 65536 + jj * 256 + threadIdx.x];
    __syncthreads();
    const float* T1l = T1 + ((size_t)l << 20);
    for (int colq = 0; colq < 4; colq++) {
        int col = colq * 256 + threadIdx.x;
        float acc = 0.f;
#pragma unroll 4
        for (int m = 0; m < 256; m++) {
            int p = ((m & 3) << 8) + (g << 6) + (m >> 2);
            acc = fmaf(sA3[m], T1l[p * 1024 + col], acc);
        }
        M[((size_t)(l << 10) + c) * 1024 + col] = acc;
    }
}

__global__ void __launch_bounds__(1024, 1)
persist(const float* __restrict__ x, const float* __restrict__ xT, int has_xt,
        const float* __restrict__ wih, const float* __restrict__ whh,
        const float* __restrict__ bih, const float* __restrict__ bhh,
        const float* __restrict__ Mc, const float* __restrict__ a4,
        float* __restrict__ ws, float* __restrict__ out) {
    __shared__ float wA[2][2][6][512];   // [l][f][d] d: gate*2+side (side0=in,1=h)
    __shared__ float wM[2][4][1024];
    __shared__ float wD[2][2][1024];
    __shared__ float red2[12][16][64];
    __shared__ float bb[2][2][4];
    __shared__ float sH[2][64];

    const int tid = threadIdx.x, w = tid >> 6, lane = tid & 63, bid = blockIdx.x;

    for (int i = tid; i < 12288; i += 1024) {
        int l = i / 6144, r = i % 6144, f = r / 3072, r2 = r % 3072, d = r2 / 512, k = r2 & 511;
        int gate = d >> 1, side = d & 1;
        int j = 2 * bid + f;
        const float* src = side ? whh : wih;
        wA[l][f][d][k] = src[l * 786432 + (gate * 512 + j) * 512 + k];
    }
    for (int i = tid; i < 8192; i += 1024) {
        int l = i >> 12, r = (i >> 10) & 3, col = i & 1023;
        wM[l][r][col] = Mc[((size_t)(l << 10) + 4 * bid + r) * 1024 + col];
    }
    for (int i = tid; i < 4096; i += 1024) {
        int l = i >> 11, f = (i >> 10) & 1, k = i & 1023;
        wD[l][f][k] = a4[l * 524288 + (2 * bid + f) * 1024 + k];
    }
    if (tid < 16) {
        int l = tid / 8, f = (tid / 4) & 1, g = tid & 3;
        int j = 2 * bid + f;
        float v;
        if (g == 0)      v = bih[l * 1536 + j] + bhh[l * 1536 + j];
        else if (g == 1) v = bih[l * 1536 + 512 + j] + bhh[l * 1536 + 512 + j];
        else if (g == 2) v = bih[l * 1536 + 1024 + j];
        else             v = bhh[l * 1536 + 1024 + j];
        bb[l][f][g] = v;
    }
    __syncthreads();

    float* hsG = ws + OFF_HS;
    float* hPg = ws + OFF_HP;
    float* sGg = ws + OFF_SG;
    float* uG  = ws + OFF_U;
    unsigned* c1p  = (unsigned*)(ws + OFF_CTR);
    unsigned* c2p  = c1p + 16;
    unsigned* genp = c1p + 17;
    float* redf = &red2[0][0][0];

    for (int t = 0; t < 512; t++) {
        for (int l = 0; l < 2; l++) {
            // ---- Stage A: GRU gates; wave w covers k-chunk, partials for all 12 units ----
            {
                float hprev = 0.f;
                if (w < 2) hprev = hsG[l * 32768 + (2 * bid + w) * 64 + lane];
                const float* inb = (l == 0) ? (xT + (size_t)t * 32768) : hsG;
                const float* hb  = hsG + l * 32768;
                float acc[12];
#pragma unroll
                for (int u = 0; u < 12; u++) acc[u] = 0.f;
                int k0 = w * 32;
#pragma unroll 4
                for (int kk = 0; kk < 32; kk++) {
                    int k = k0 + kk;
                    float iv;
                    if (l == 0 && !has_xt)
                        iv = x[(size_t)lane * 262144 + (size_t)t * 512 + k];
                    else
                        iv = inb[k * 64 + lane];
                    float hv = hb[k * 64 + lane];
#pragma unroll
                    for (int f = 0; f < 2; f++) {
                        acc[f * 6 + 0] = fmaf(wA[l][f][0][k], iv, acc[f * 6 + 0]);
                        acc[f * 6 + 1] = fmaf(wA[l][f][1][k], hv, acc[f * 6 + 1]);
                        acc[f * 6 + 2] = fmaf(wA[l][f][2][k], iv, acc[f * 6 + 2]);
                        acc[f * 6 + 3] = fmaf(wA[l][f][3][k], hv, acc[f * 6 + 3]);
                        acc[f * 6 + 4] = fmaf(wA[l][f][4][k], iv, acc[f * 6 + 4]);
                        acc[f * 6 + 5] = fmaf(wA[l][f][5][k], hv, acc[f * 6 + 5]);
                    }
                }
#pragma unroll
                for (int u = 0; u < 12; u++) red2[u][w][lane] = acc[u];
                __syncthreads();
                if (w < 2) {
                    int f = w;
                    float g0 = 0, g1 = 0, g2 = 0, g3 = 0, g4 = 0, g5 = 0;
#pragma unroll
                    for (int i = 0; i < 16; i++) {
                        g0 += red2[f * 6 + 0][i][lane]; g1 += red2[f * 6 + 1][i][lane];
                        g2 += red2[f * 6 + 2][i][lane]; g3 += red2[f * 6 + 3][i][lane];
                        g4 += red2[f * 6 + 4][i][lane]; g5 += red2[f * 6 + 5][i][lane];
                    }
                    float r = sigm(g0 + g1 + bb[l][f][0]);
                    float z = sigm(g2 + g3 + bb[l][f][1]);
                    float n = tanhf(g4 + bb[l][f][2] + r * (g5 + bb[l][f][3]));
                    float hp = (1.f - z) * n + z * hprev;
                    sH[f][lane] = hp;
                    hPg[(2 * bid + f) * 64 + lane] = hp;
                }
            }
            gbar(c1p, c2p, genp);

            // ---- Stage B: rank-sort scatter ----
            {
                int f = w & 1, ch = w >> 1;
                int j = 2 * bid + f;
                float v = sH[f][lane];
                int cnt = 0;
                int k0 = ch * 64;
#pragma unroll 8
                for (int kk = 0; kk < 64; kk++) {
                    int k = k0 + kk;
                    float hv = hPg[k * 64 + lane];
                    cnt += (hv < v || (hv == v && k < j)) ? 1 : 0;
                }
                redf[w * 64 + lane] = (float)cnt;
                __syncthreads();
                if (w < 2) {
                    int rk = 0;
#pragma unroll
                    for (int ch2 = 0; ch2 < 8; ch2++)
                        rk += (int)redf[(ch2 * 2 + w) * 64 + lane];
                    sGg[rk * 64 + lane] = sH[w][lane];
                }
            }
            gbar(c1p, c2p, genp);

            // ---- Stage C: u = relu(M [h; s]) ----
            {
                float acc[4] = {0.f, 0.f, 0.f, 0.f};
                int k0 = w * 64;
                const float* src = (k0 < 512) ? (hPg + k0 * 64) : (sGg + (k0 - 512) * 64);
#pragma unroll 4
                for (int kk = 0; kk < 64; kk++) {
                    float vv = src[kk * 64 + lane];
                    int k = k0 + kk;
#pragma unroll
                    for (int r = 0; r < 4; r++)
                        acc[r] = fmaf(wM[l][r][k], vv, acc[r]);
                }
#pragma unroll
                for (int r = 0; r < 4; r++) red2[r][w][lane] = acc[r];
                __syncthreads();
                if (w < 4) {
                    float s = 0.f;
#pragma unroll
                    for (int i = 0; i < 16; i++) s += red2[w][i][lane];
                    uG[(4 * bid + w) * 64 + lane] = fmaxf(s, 0.f);
                }
            }
            gbar(c1p, c2p, genp);

            // ---- Stage D: scores + state update ----
            {
                float acc0 = 0.f, acc1 = 0.f;
                int k0 = w * 64;
#pragma unroll 4
                for (int kk = 0; kk < 64; kk++) {
                    int k = k0 + kk;
                    float vv = uG[k * 64 + lane];
                    acc0 = fmaf(wD[l][0][k], vv, acc0);
                    acc1 = fmaf(wD[l][1][k], vv, acc1);
                }
                red2[0][w][lane] = acc0;
                red2[1][w][lane] = acc1;
                __syncthreads();
                if (w < 2) {
                    float s = 0.f;
#pragma unroll
                    for (int i = 0; i < 16; i++) s += red2[w][i][lane];
                    float hnew = sH[w][lane] * sigm(s);
                    hsG[l * 32768 + (2 * bid + w) * 64 + lane] = hnew;
                    if (l == 1)
                        out[(size_t)lane * 262144 + (size_t)t * 512 + (2 * bid + w)] = hnew;
                }
            }
            gbar(c1p, c2p, genp);
        }
    }
}

extern "C" void kernel_launch(void* const* d_in, const int* in_sizes, int n_in,
                              void* d_out, int out_size, void* d_ws, size_t ws_size,
                              hipStream_t stream) {
    const float* x   = (const float*)d_in[0];
    const float* h0  = (const float*)d_in[1];
    const float* wih = (const float*)d_in[2];
    const float* whh = (const float*)d_in[3];
    const float* bih = (const float*)d_in[4];
    const float* bhh = (const float*)d_in[5];
    const float* a1  = (const float*)d_in[6];
    const float* a2  = (const float*)d_in[7];
    const float* a3  = (const float*)d_in[8];
    const float* a4  = (const float*)d_in[9];
    float* ws  = (float*)d_ws;
    float* out = (float*)d_out;

    int has_xt = (ws_size >= (size_t)WS_FULL * 4) ? 1 : 0;
    float* T1p = ws + OFF_T1;
    float* Mp  = ws + OFF_M;
    const float* xTp = ws + OFF_XT;

    hipLaunchKernelGGL(k_init, dim3(256), dim3(256), 0, stream, h0, ws);
    if (has_xt)
        hipLaunchKernelGGL(k_xtk, dim3(4096), dim3(256), 0, stream, x, ws + OFF_XT);
    hipLaunchKernelGGL(k_t1, dim3(2048), dim3(256), 0, stream, a1, a2, T1p);
    hipLaunchKernelGGL(k_m, dim3(2048), dim3(256), 0, stream, a3, T1p, Mp);

    void* args[] = {(void*)&x, (void*)&xTp, (void*)&has_xt,
                    (void*)&wih, (void*)&whh, (void*)&bih, (void*)&bhh,
                    (void*)&Mp, (void*)&a4, (void*)&ws, (void*)&out};
    hipLaunchCooperativeKernel((void*)persist, dim3(256), dim3(1024), args, 0, stream);
}

// Round 5
// 111697.815 us; speedup vs baseline: 2.0549x; 1.0575x over previous
//
#include <hip/hip_runtime.h>

#define SCOPE_AGENT __HIP_MEMORY_SCOPE_AGENT

// ws layout (float offsets)
#define OFF_HS    0          // [2][512][64] hidden states
#define OFF_HP    65536      // [512][64] h'
#define OFF_SG    98304      // [512][64] sorted
#define OFF_U     131072     // [1024][64] u = relu(M [h;s])
#define OFF_CTR   196608     // 18 uints barrier
#define OFF_T1    262144     // [2][1024][1024] compose scratch
#define OFF_M     2359296    // [2][1024][1024] composed M
#define OFF_GIX   4456448    // [512][512][3][64] precomputed W_ih. x_t (layer 0)
#define OFF_XT    4456448    // fallback: [512][512][64] transposed x
#define WS_GIX    54788096   // floats incl gix (219 MB)
#define WS_XT     21233664   // floats incl xT (85 MB)

__device__ __forceinline__ float sigm(float x) { return 1.f / (1.f + expf(-x)); }

__device__ __forceinline__ float ld_sc1(const float* p) {
    return __hip_atomic_load(p, __ATOMIC_RELAXED, SCOPE_AGENT);
}
__device__ __forceinline__ void st_sc1(float* p, float v) {
    __hip_atomic_store(p, v, __ATOMIC_RELAXED, SCOPE_AGENT);
}

// pure fan-in barrier: relaxed atomics only (no wbl2/inv). Ordering: __syncthreads
// drains each wave's vmem (sc1 stores ack'd at L3) before thread0 arrives.
__device__ __forceinline__ void gbar(unsigned* c1, unsigned* c2, unsigned* gen) {
    __syncthreads();
    if (threadIdx.x == 0) {
        __atomic_signal_fence(__ATOMIC_SEQ_CST);
        unsigned g = __hip_atomic_load(gen, __ATOMIC_RELAXED, SCOPE_AGENT);
        unsigned a = __hip_atomic_fetch_add(&c1[blockIdx.x & 15], 1u, __ATOMIC_RELAXED, SCOPE_AGENT);
        bool last = false;
        if (a == 15u) {
            unsigned b = __hip_atomic_fetch_add(c2, 1u, __ATOMIC_RELAXED, SCOPE_AGENT);
            if (b == 15u) {
                last = true;
                for (int i = 0; i < 16; i++)
                    __hip_atomic_store(&c1[i], 0u, __ATOMIC_RELAXED, SCOPE_AGENT);
                __hip_atomic_store(c2, 0u, __ATOMIC_RELAXED, SCOPE_AGENT);
                __hip_atomic_store(gen, g + 1u, __ATOMIC_RELAXED, SCOPE_AGENT);
            }
        }
        if (!last) {
            while (__hip_atomic_load(gen, __ATOMIC_RELAXED, SCOPE_AGENT) == g)
                __builtin_amdgcn_s_sleep(1);
        }
        __atomic_signal_fence(__ATOMIC_SEQ_CST);
    }
    __syncthreads();
}

__global__ void k_init(const float* __restrict__ h0, float* __restrict__ ws) {
    int idx = blockIdx.x * blockDim.x + threadIdx.x;   // 65536
    int l = idx >> 15, k = (idx & 32767) >> 6;
    ws[OFF_HS + idx] = h0[(l << 9) + k];
    if (idx < 18) ((unsigned*)(ws + OFF_CTR))[idx] = 0u;
}

// gix[t][j][g][b] = sum_k wih0[g*512+j][k] * x[b][t*512+k]
__global__ void k_gix(const float* __restrict__ x, const float* __restrict__ wih,
                      float* __restrict__ gix) {
    __shared__ float xs[128][65];
    __shared__ float ww[32][129];
    int t = blockIdx.x, rb = blockIdx.y * 32;
    int tid = threadIdx.x;
    int rw = tid >> 6, b = tid & 63;
    float acc[8] = {0.f, 0.f, 0.f, 0.f, 0.f, 0.f, 0.f, 0.f};
    for (int kc = 0; kc < 4; kc++) {
        __syncthreads();
        for (int i = tid; i < 8192; i += 256) {
            int k = i & 127, b2 = i >> 7;
            xs[k][b2] = x[(size_t)b2 * 262144 + (size_t)t * 512 + kc * 128 + k];
        }
        for (int i = tid; i < 4096; i += 256) {
            int r = i >> 7, k = i & 127;
            ww[r][k] = wih[(size_t)(rb + r) * 512 + kc * 128 + k];
        }
        __syncthreads();
        for (int k = 0; k < 128; k++) {
            float xv = xs[k][b];
#pragma unroll
            for (int rr = 0; rr < 8; rr++)
                acc[rr] = fmaf(ww[rw * 8 + rr][k], xv, acc[rr]);
        }
    }
#pragma unroll
    for (int rr = 0; rr < 8; rr++) {
        int rg = rb + rw * 8 + rr;
        int g = rg >> 9, j = rg & 511;
        gix[((size_t)((size_t)t * 512 + j) * 3 + g) * 64 + b] = acc[rr];
    }
}

// fallback transpose x -> xT[t][k][b]
__global__ void k_xtk(const float* __restrict__ x, float* __restrict__ xT) {
    __shared__ float tile[64][65];
    int t = blockIdx.x >> 3, kc = blockIdx.x & 7;
    int k = threadIdx.x & 63, b0 = threadIdx.x >> 6;
    for (int i = 0; i < 16; i++) {
        int b = i * 4 + b0;
        tile[k][b] = x[(size_t)b * 262144 + (size_t)t * 512 + kc * 64 + k];
    }
    __syncthreads();
    int b2 = threadIdx.x & 63, k0 = threadIdx.x >> 6;
    for (int i = 0; i < 16; i++) {
        int k2 = i * 4 + k0;
        xT[((size_t)t * 512 + kc * 64 + k2) * 64 + b2] = tile[k2][b2];
    }
}

// T1 = C2p * C1
__global__ void k_t1(const float* __restrict__ a1, const float* __restrict__ a2,
                     float* __restrict__ T1) {
    int l = blockIdx.x >> 10, c = blockIdx.x & 1023;
    int g = c >> 8, jj = c & 255;
    __shared__ float sA2[256];
    sA2[threadIdx.x] = a2[l * 65536 + jj * 256 + threadIdx.x];
    __syncthreads();
    const float* A1l = a1 + l * 262144;
    for (int colq = 0; colq < 4; colq++) {
        int col = colq * 256 + threadIdx.x;
        int half = col >> 9, cm = col & 511;
        float acc = 0.f;
#pragma unroll 4
        for (int q = 0; q < 64; q++) {
            int a0 = 2 * half;
            int j0 = g * 64 + q;
            acc = fmaf(sA2[4 * q + a0],     A1l[j0 * 512 + cm], acc);
            acc = fmaf(sA2[4 * q + a0 + 1], A1l[(j0 + 256) * 512 + cm], acc);
        }
        T1[((size_t)(l << 10) + c) * 1024 + col] = acc;
    }
}

// M = C3p * T1
__global__ void k_m(const float* __restrict__ a3, const float* __restrict__ T1,
                    float* __restrict__ M) {
    int l = blockIdx.x >> 10, c = blockIdx.x & 1023;
    int g = c >> 8, jj = c & 255;
    __shared__ float sA3[256];
    sA3[threadIdx.x] = a3[l * 65536 + jj * 256 + threadIdx.x];
    __syncthreads();
    const float* T1l = T1 + ((size_t)l << 20);
    for (int colq = 0; colq < 4; colq++) {
        int col = colq * 256 + threadIdx.x;
        float acc = 0.f;
#pragma unroll 4
        for (int m = 0; m < 256; m++) {
            int p = ((m & 3) << 8) + (g << 6) + (m >> 2);
            acc = fmaf(sA3[m], T1l[p * 1024 + col], acc);
        }
        M[((size_t)(l << 10) + c) * 1024 + col] = acc;
    }
}

__global__ void __launch_bounds__(1024, 1)
persist(const float* __restrict__ x, const float* __restrict__ xT,
        const float* __restrict__ gix, int has_xt, int has_gix,
        const float* __restrict__ wih, const float* __restrict__ whh,
        const float* __restrict__ bih, const float* __restrict__ bhh,
        const float* __restrict__ Mc, const float* __restrict__ a4,
        float* __restrict__ ws, float* __restrict__ out) {
    __shared__ float wA[2][2][6][512];   // [l][f][d] d = gate*2+side (0=in,1=h)
    __shared__ float wM[2][4][1024];
    __shared__ float wD[2][2][1024];
    __shared__ float red2[12][16][64];
    __shared__ float bb[2][2][4];
    __shared__ float sH[2][64];

    const int tid = threadIdx.x, w = tid >> 6, lane = tid & 63, bid = blockIdx.x;

    for (int i = tid; i < 12288; i += 1024) {
        int l = i / 6144, r = i % 6144, f = r / 3072, r2 = r % 3072, d = r2 / 512, k = r2 & 511;
        int gate = d >> 1, side = d & 1;
        int j = 2 * bid + f;
        const float* src = side ? whh : wih;
        wA[l][f][d][k] = src[l * 786432 + (gate * 512 + j) * 512 + k];
    }
    for (int i = tid; i < 8192; i += 1024) {
        int l = i >> 12, r = (i >> 10) & 3, col = i & 1023;
        wM[l][r][col] = Mc[((size_t)(l << 10) + 4 * bid + r) * 1024 + col];
    }
    for (int i = tid; i < 4096; i += 1024) {
        int l = i >> 11, f = (i >> 10) & 1, k = i & 1023;
        wD[l][f][k] = a4[l * 524288 + (2 * bid + f) * 1024 + k];
    }
    if (tid < 16) {
        int l = tid / 8, f = (tid / 4) & 1, g = tid & 3;
        int j = 2 * bid + f;
        float v;
        if (g == 0)      v = bih[l * 1536 + j] + bhh[l * 1536 + j];
        else if (g == 1) v = bih[l * 1536 + 512 + j] + bhh[l * 1536 + 512 + j];
        else if (g == 2) v = bih[l * 1536 + 1024 + j];
        else             v = bhh[l * 1536 + 1024 + j];
        bb[l][f][g] = v;
    }
    __syncthreads();

    float* hsG = ws + OFF_HS;
    float* hPg = ws + OFF_HP;
    float* sGg = ws + OFF_SG;
    float* uG  = ws + OFF_U;
    unsigned* c1p  = (unsigned*)(ws + OFF_CTR);
    unsigned* c2p  = c1p + 16;
    unsigned* genp = c1p + 17;

    for (int t = 0; t < 512; t++) {
        for (int l = 0; l < 2; l++) {
            // ---- Stage A: GRU gates + h' ----
            {
                float hprev = 0.f;
                if (w < 2) hprev = ld_sc1(&hsG[l * 32768 + (2 * bid + w) * 64 + lane]);
                const float* hb = hsG + l * 32768;
                int k0 = w * 32;
                if (l == 0 && has_gix) {
                    float acc[6];
#pragma unroll
                    for (int u = 0; u < 6; u++) acc[u] = 0.f;
#pragma unroll 8
                    for (int kk = 0; kk < 32; kk++) {
                        int k = k0 + kk;
                        float hv = ld_sc1(&hb[k * 64 + lane]);
#pragma unroll
                        for (int f = 0; f < 2; f++) {
                            acc[f * 3 + 0] = fmaf(wA[0][f][1][k], hv, acc[f * 3 + 0]);
                            acc[f * 3 + 1] = fmaf(wA[0][f][3][k], hv, acc[f * 3 + 1]);
                            acc[f * 3 + 2] = fmaf(wA[0][f][5][k], hv, acc[f * 3 + 2]);
                        }
                    }
#pragma unroll
                    for (int u = 0; u < 6; u++) red2[u][w][lane] = acc[u];
                    __syncthreads();
                    if (w < 2) {
                        int f = w, j = 2 * bid + f;
                        float s0 = 0, s1 = 0, s2 = 0;
#pragma unroll
                        for (int i = 0; i < 16; i++) {
                            s0 += red2[f * 3 + 0][i][lane];
                            s1 += red2[f * 3 + 1][i][lane];
                            s2 += red2[f * 3 + 2][i][lane];
                        }
                        const float* gx = gix + ((size_t)((size_t)t * 512 + j) * 3) * 64;
                        float r = sigm(gx[lane] + s0 + bb[0][f][0]);
                        float z = sigm(gx[64 + lane] + s1 + bb[0][f][1]);
                        float n = tanhf(gx[128 + lane] + bb[0][f][2] + r * (s2 + bb[0][f][3]));
                        float hp = (1.f - z) * n + z * hprev;
                        sH[f][lane] = hp;
                        st_sc1(&hPg[j * 64 + lane], hp);
                    }
                } else {
                    float acc[12];
#pragma unroll
                    for (int u = 0; u < 12; u++) acc[u] = 0.f;
#pragma unroll 8
                    for (int kk = 0; kk < 32; kk++) {
                        int k = k0 + kk;
                        float iv;
                        if (l == 1)            iv = ld_sc1(&hsG[k * 64 + lane]);
                        else if (has_xt)       iv = xT[(size_t)t * 32768 + k * 64 + lane];
                        else                   iv = x[(size_t)lane * 262144 + (size_t)t * 512 + k];
                        float hv = ld_sc1(&hb[k * 64 + lane]);
#pragma unroll
                        for (int f = 0; f < 2; f++) {
                            acc[f * 6 + 0] = fmaf(wA[l][f][0][k], iv, acc[f * 6 + 0]);
                            acc[f * 6 + 1] = fmaf(wA[l][f][1][k], hv, acc[f * 6 + 1]);
                            acc[f * 6 + 2] = fmaf(wA[l][f][2][k], iv, acc[f * 6 + 2]);
                            acc[f * 6 + 3] = fmaf(wA[l][f][3][k], hv, acc[f * 6 + 3]);
                            acc[f * 6 + 4] = fmaf(wA[l][f][4][k], iv, acc[f * 6 + 4]);
                            acc[f * 6 + 5] = fmaf(wA[l][f][5][k], hv, acc[f * 6 + 5]);
                        }
                    }
#pragma unroll
                    for (int u = 0; u < 12; u++) red2[u][w][lane] = acc[u];
                    __syncthreads();
                    if (w < 2) {
                        int f = w, j = 2 * bid + f;
                        float g0 = 0, g1 = 0, g2 = 0, g3 = 0, g4 = 0, g5 = 0;
#pragma unroll
                        for (int i = 0; i < 16; i++) {
                            g0 += red2[f * 6 + 0][i][lane]; g1 += red2[f * 6 + 1][i][lane];
                            g2 += red2[f * 6 + 2][i][lane]; g3 += red2[f * 6 + 3][i][lane];
                            g4 += red2[f * 6 + 4][i][lane]; g5 += red2[f * 6 + 5][i][lane];
                        }
                        float r = sigm(g0 + g1 + bb[l][f][0]);
                        float z = sigm(g2 + g3 + bb[l][f][1]);
                        float n = tanhf(g4 + bb[l][f][2] + r * (g5 + bb[l][f][3]));
                        float hp = (1.f - z) * n + z * hprev;
                        sH[f][lane] = hp;
                        st_sc1(&hPg[j * 64 + lane], hp);
                    }
                }
            }
            gbar(c1p, c2p, genp);

            // ---- Stage B: rank of both block features over one 32-chunk per wave ----
            {
                int j0 = 2 * bid, j1 = j0 + 1;
                float v0 = sH[0][lane], v1 = sH[1][lane];
                int k0 = w * 32, cnt0 = 0, cnt1 = 0;
#pragma unroll 8
                for (int kk = 0; kk < 32; kk++) {
                    int k = k0 + kk;
                    float hv = ld_sc1(&hPg[k * 64 + lane]);
                    cnt0 += (hv < v0 || (hv == v0 && k < j0)) ? 1 : 0;
                    cnt1 += (hv < v1 || (hv == v1 && k < j1)) ? 1 : 0;
                }
                red2[0][w][lane] = (float)cnt0;
                red2[1][w][lane] = (float)cnt1;
                __syncthreads();
                if (w < 2) {
                    int rk = 0;
#pragma unroll
                    for (int i = 0; i < 16; i++) rk += (int)red2[w][i][lane];
                    st_sc1(&sGg[rk * 64 + lane], sH[w][lane]);
                }
            }
            gbar(c1p, c2p, genp);

            // ---- Stage C: u = relu(M [h; s]) ----
            {
                float acc[4] = {0.f, 0.f, 0.f, 0.f};
                int k0 = w * 64;
                const float* src = (k0 < 512) ? &hPg[k0 * 64] : &sGg[(k0 - 512) * 64];
#pragma unroll 8
                for (int kk = 0; kk < 64; kk++) {
                    float vv = ld_sc1(&src[kk * 64 + lane]);
                    int k = k0 + kk;
#pragma unroll
                    for (int r = 0; r < 4; r++)
                        acc[r] = fmaf(wM[l][r][k], vv, acc[r]);
                }
#pragma unroll
                for (int r = 0; r < 4; r++) red2[r][w][lane] = acc[r];
                __syncthreads();
                if (w < 4) {
                    float s = 0.f;
#pragma unroll
                    for (int i = 0; i < 16; i++) s += red2[w][i][lane];
                    st_sc1(&uG[(4 * bid + w) * 64 + lane], fmaxf(s, 0.f));
                }
            }
            gbar(c1p, c2p, genp);

            // ---- Stage D: scores + state update ----
            {
                float a0 = 0.f, a1v = 0.f;
                int k0 = w * 64;
#pragma unroll 8
                for (int kk = 0; kk < 64; kk++) {
                    int k = k0 + kk;
                    float vv = ld_sc1(&uG[k * 64 + lane]);
                    a0 = fmaf(wD[l][0][k], vv, a0);
                    a1v = fmaf(wD[l][1][k], vv, a1v);
                }
                red2[0][w][lane] = a0;
                red2[1][w][lane] = a1v;
                __syncthreads();
                if (w < 2) {
                    float s = 0.f;
#pragma unroll
                    for (int i = 0; i < 16; i++) s += red2[w][i][lane];
                    float hnew = sH[w][lane] * sigm(s);
                    st_sc1(&hsG[l * 32768 + (2 * bid + w) * 64 + lane], hnew);
                    if (l == 1)
                        out[(size_t)lane * 262144 + (size_t)t * 512 + (2 * bid + w)] = hnew;
                }
            }
            gbar(c1p, c2p, genp);
        }
    }
}

extern "C" void kernel_launch(void* const* d_in, const int* in_sizes, int n_in,
                              void* d_out, int out_size, void* d_ws, size_t ws_size,
                              hipStream_t stream) {
    const float* x   = (const float*)d_in[0];
    const float* h0  = (const float*)d_in[1];
    const float* wih = (const float*)d_in[2];
    const float* whh = (const float*)d_in[3];
    const float* bih = (const float*)d_in[4];
    const float* bhh = (const float*)d_in[5];
    const float* a1  = (const float*)d_in[6];
    const float* a2  = (const float*)d_in[7];
    const float* a3  = (const float*)d_in[8];
    const float* a4  = (const float*)d_in[9];
    float* ws  = (float*)d_ws;
    float* out = (float*)d_out;

    int has_gix = (ws_size >= (size_t)WS_GIX * 4) ? 1 : 0;
    int has_xt  = (!has_gix && ws_size >= (size_t)WS_XT * 4) ? 1 : 0;
    float* T1p = ws + OFF_T1;
    float* Mp  = ws + OFF_M;
    const float* gixp = ws + OFF_GIX;
    const float* xTp  = ws + OFF_XT;

    hipLaunchKernelGGL(k_init, dim3(256), dim3(256), 0, stream, h0, ws);
    if (has_gix)
        hipLaunchKernelGGL(k_gix, dim3(512, 48), dim3(256), 0, stream, x, wih, ws + OFF_GIX);
    else if (has_xt)
        hipLaunchKernelGGL(k_xtk, dim3(4096), dim3(256), 0, stream, x, ws + OFF_XT);
    hipLaunchKernelGGL(k_t1, dim3(2048), dim3(256), 0, stream, a1, a2, T1p);
    hipLaunchKernelGGL(k_m, dim3(2048), dim3(256), 0, stream, a3, T1p, Mp);

    void* args[] = {(void*)&x, (void*)&xTp, (void*)&gixp, (void*)&has_xt, (void*)&has_gix,
                    (void*)&wih, (void*)&whh, (void*)&bih, (void*)&bhh,
                    (void*)&Mp, (void*)&a4, (void*)&ws, (void*)&out};
    hipLaunchCooperativeKernel((void*)persist, dim3(256), dim3(1024), args, 0, stream);
}